// Round 7
// baseline (435.467 us; speedup 1.0000x reference)
//
#include <hip/hip_runtime.h>
#include <hip/hip_bf16.h>

#define N_NODES 20000
#define T_STEPS 8
#define E_EDGES 320000
#define HID 128
#define BN 80                          // nodes per gru block: 250 blocks exactly

typedef short short8 __attribute__((ext_vector_type(8)));
typedef float f32x4 __attribute__((ext_vector_type(4)));

// ---- all scratch in device globals: independent of ws_size ----------------
__device__ __attribute__((aligned(16))) float g_xT[T_STEPS * N_NODES];
__device__ __attribute__((aligned(16))) float g_ndf[T_STEPS * N_NODES * 4];
__device__ __attribute__((aligned(16))) int   g_cnt[N_NODES];
__device__ __attribute__((aligned(16))) int   g_rowptr[N_NODES + 1];
__device__ __attribute__((aligned(16))) int   g_cursor[N_NODES];
__device__ __attribute__((aligned(16))) int   g_sorted[E_EDGES];
__device__ __attribute__((aligned(16))) short g_w1hi[65536];
__device__ __attribute__((aligned(16))) short g_w1lo[65536];
__device__ __attribute__((aligned(16))) short g_w2hi[32768];
__device__ __attribute__((aligned(16))) short g_w2lo[32768];
__device__ float g_lin[6];            // P,Q,R per head
__device__ int   g_flag;

__device__ __forceinline__ float fsig(float z) {
    return 1.0f / (1.0f + __expf(-z));
}
__device__ __forceinline__ unsigned short f2bf(float f) {
    unsigned u = __builtin_bit_cast(unsigned, f);
    unsigned r = (u + 0x7FFFu + ((u >> 16) & 1u)) >> 16;   // RTNE
    return (unsigned short)r;
}
__device__ __forceinline__ float bf2f(unsigned short s) {
    return __builtin_bit_cast(float, ((unsigned)s) << 16);
}

// ---------------------------------------------------------------------------
__global__ void detect_kernel(const unsigned int* __restrict__ ei32) {
    int all_zero = 1;
    for (int k = 0; k < 64; ++k)
        if (ei32[2 * k + 1] != 0u) { all_zero = 0; break; }
    g_flag = all_zero;   // 1 => int64 layout
}

__device__ __forceinline__ void load_edge(const void* ei, int e, int& src, int& dst) {
    if (g_flag) {
        const long long* p = (const long long*)ei;
        src = (int)p[e]; dst = (int)p[E_EDGES + e];
    } else {
        const int* p = (const int*)ei;
        src = p[e]; dst = p[E_EDGES + e];
    }
}

// ---------------------------------------------------------------------------
__global__ __launch_bounds__(256) void init_kernel(
    const float* __restrict__ x, const void* __restrict__ ei)
{
    const int i = blockIdx.x * 256 + threadIdx.x;
    if (i < T_STEPS * N_NODES) {
        const int n = i >> 3, t = i & 7;
        g_xT[t * N_NODES + n] = x[i];
    }
    if (i < N_NODES) g_cnt[i] = 0;
}

__global__ __launch_bounds__(256) void hist_kernel(const void* __restrict__ ei) {
    const int e = blockIdx.x * 256 + threadIdx.x;
    if (e >= E_EDGES) return;
    int src, dst; load_edge(ei, e, src, dst);
    atomicAdd(&g_cnt[dst], 1);
}

// single block, 1024 threads: exclusive scan of g_cnt -> g_rowptr, g_cursor
__global__ __launch_bounds__(1024) void scan_kernel() {
    __shared__ int part[1024];
    const int tid  = threadIdx.x;
    const int base = tid * 20;
    int local[20];
    int s = 0;
    #pragma unroll
    for (int i = 0; i < 20; ++i) {
        const int n = base + i;
        const int c = (n < N_NODES) ? g_cnt[n] : 0;
        local[i] = s; s += c;
    }
    part[tid] = s;
    __syncthreads();
    for (int off = 1; off < 1024; off <<= 1) {
        const int v = (tid >= off) ? part[tid - off] : 0;
        __syncthreads();
        part[tid] += v;
        __syncthreads();
    }
    const int pre = (tid == 0) ? 0 : part[tid - 1];
    #pragma unroll
    for (int i = 0; i < 20; ++i) {
        const int n = base + i;
        if (n < N_NODES) {
            const int v = pre + local[i];
            g_rowptr[n] = v;
            g_cursor[n] = v;
        }
    }
    if (tid == 1023) g_rowptr[N_NODES] = part[1023];
}

__global__ __launch_bounds__(256) void scatter_kernel(const void* __restrict__ ei) {
    const int e = blockIdx.x * 256 + threadIdx.x;
    if (e >= E_EDGES) return;
    int src, dst; load_edge(ei, e, src, dst);
    const int pos = atomicAdd(&g_cursor[dst], 1);
    g_sorted[pos] = src;
}

// ---------------------------------------------------------------------------
// Prep: pack transposed bf16 hi/lo W1,W2 fragments; compute P,Q,R per head.
// Layout: idx = ((kb*NCOLS + n)*4 + kq)*8 + r  holds  W[kb*32+kq*8+r][n]
// ---------------------------------------------------------------------------
__global__ __launch_bounds__(256) void prep_kernel(
    const float* __restrict__ W1, const float* __restrict__ W2,
    const float* __restrict__ W_l, const float* __restrict__ b_l,
    const float* __restrict__ W_r, const float* __restrict__ b_r,
    const float* __restrict__ att)
{
    int i = blockIdx.x * 256 + threadIdx.x;   // 0 .. 98303
    if (i < 65536) {                          // W1: (256,256) [k][n]
        int k = i >> 8, n = i & 255;
        float w = W1[i];
        int kb = k >> 5, kq = (k >> 3) & 3, r = k & 7;
        int idx = ((kb * 256 + n) * 4 + kq) * 8 + r;
        unsigned short hi = f2bf(w);
        g_w1hi[idx] = (short)hi;
        g_w1lo[idx] = (short)f2bf(w - bf2f(hi));
    } else {                                  // W2: (256,128) [k][n]
        int j = i - 65536;
        int k = j >> 7, n = j & 127;
        float w = W2[j];
        int kb = k >> 5, kq = (k >> 3) & 3, r = k & 7;
        int idx = ((kb * 128 + n) * 4 + kq) * 8 + r;
        unsigned short hi = f2bf(w);
        g_w2hi[idx] = (short)hi;
        g_w2lo[idx] = (short)f2bf(w - bf2f(hi));
    }
    if (blockIdx.x == 0 && threadIdx.x < 2) {
        const int hh = threadIdx.x;
        float P = 0.f, Q = 0.f, R = 0.f;
        for (int k = 0; k < 64; ++k) {
            const int c = hh * 64 + k;
            const float a = att[c];
            P = fmaf(a, W_l[c], P);
            Q = fmaf(a, W_r[c], Q);
            R = fmaf(a, b_l[c] + b_r[c], R);
        }
        g_lin[hh * 3 + 0] = P;
        g_lin[hh * 3 + 1] = Q;
        g_lin[hh * 3 + 2] = R;
    }
}

// ---------------------------------------------------------------------------
// Edge pass, all 8 timesteps, no atomics.
// ---------------------------------------------------------------------------
__global__ __launch_bounds__(256) void edge_all_kernel(
    const float* __restrict__ W_l, const float* __restrict__ b_l,
    const float* __restrict__ W_r, const float* __restrict__ b_r,
    const float* __restrict__ att)
{
    __shared__ float4 ch4[128];
    const int tid = threadIdx.x;
    if (tid < 128)
        ch4[tid] = make_float4(W_l[tid], W_r[tid], b_l[tid] + b_r[tid], att[tid]);
    __syncthreads();

    const int n    = blockIdx.x * 128 + (tid >> 1);
    const int head = tid & 1;
    const int t    = blockIdx.y;
    if (n >= N_NODES) return;

    const float* xrow = &g_xT[t * N_NODES];
    const float xd = xrow[n];
    const float P = g_lin[head * 3 + 0];
    const float Q = g_lin[head * 3 + 1];
    const float R = g_lin[head * 3 + 2];
    const float4* chh = &ch4[head * 64];

    const int base = g_rowptr[n];
    const int deg  = g_rowptr[n + 1] - base;
    const int tot  = deg + 1;            // +1 = self loop at idx 0

    float den = 0.f, num = 0.f;
    for (int cs = 0; cs < tot; cs += 8) {
        int m = tot - cs; if (m > 8) m = 8;
        float xs[8];
        #pragma unroll
        for (int e = 0; e < 8; ++e) {
            xs[e] = 0.f;
            if (e < m) {
                const int idx = cs + e;
                xs[e] = (idx == 0) ? xd : xrow[g_sorted[base + idx - 1]];
            }
        }
        float ea[8];
        #pragma unroll
        for (int e = 0; e < 8; ++e) ea[e] = 0.f;
        #pragma unroll 4
        for (int c = 0; c < 64; ++c) {
            const float4 f = chh[c];
            const float dpart = fmaf(xd, f.y, f.z);
            #pragma unroll
            for (int e = 0; e < 8; ++e) {
                const float a = fmaf(xs[e], f.x, dpart);
                ea[e] = fmaf(fabsf(a), f.w, ea[e]);
            }
        }
        #pragma unroll
        for (int e = 0; e < 8; ++e) {
            if (e < m) {
                const float ee = fmaf(0.6f, fmaf(xs[e], P, fmaf(xd, Q, R)), 0.4f * ea[e]);
                const float ex = __expf(ee);
                den += ex;
                num = fmaf(ex, xs[e], num);
            }
        }
    }
    g_ndf[((size_t)t * N_NODES + n) * 4 + head]     = den;
    g_ndf[((size_t)t * N_NODES + n) * 4 + 2 + head] = num;
}

// ---------------------------------------------------------------------------
// GRU v3: BN=80, 250 blocks, 1024 threads (16 waves, 4/SIMD).
// Waves 0-7 (r-waves): GEMM1 r-cols [0,128), GEMM2 K-low half, h in hreg[5].
// Waves 8-15 (u-waves): GEMM1 u-cols [128,256), GEMM2 K-high half -> pbuf.
// featA row = 384 shorts: [f: g0-15 | hbf: g16-31 | rh: g32-47], XOR granule
// swizzle g^(node&7) (segment-preserving). 3 barriers/step.
// ---------------------------------------------------------------------------
__global__ __launch_bounds__(1024) void gru_all_kernel(
    const float* __restrict__ W_l, const float* __restrict__ b_l,
    const float* __restrict__ conv_bias,
    const float* __restrict__ b1, const float* __restrict__ b2,
    float* __restrict__ hout)
{
    __shared__ short featA[BN * 384];   // 61440 B
    __shared__ short ubuf[BN * 136];    // 21760 B (padded row)
    __shared__ float pbuf[BN * 132];    // 42240 B (padded row)
    __shared__ float swl[128], sbl[128], scb[128], sb1a[128], sb1b[128], sb2[128];

    const int t   = threadIdx.x;
    const int n0g = blockIdx.x * BN;

    if (t < 128) {
        swl[t] = W_l[t]; sbl[t] = b_l[t]; scb[t] = conv_bias[t];
        sb1a[t] = b1[t]; sb1b[t] = b1[128 + t]; sb2[t] = b2[t];
    }
    // zero hbf segment (granules 16..31): 1280 granule tasks
    for (int i = t; i < BN * 16; i += 1024) {
        const int node = i >> 4;
        const int g    = 16 + (i & 15);
        const int gsw  = g ^ (node & 7);
        *(short8*)&featA[node * 384 + gsw * 8] = (short8)0;
    }
    __syncthreads();

    const int wid = t >> 6;
    const int l   = t & 63;
    const int lr  = l & 15;
    const int lk  = l >> 4;
    const bool rw = (wid < 8);
    const int ec  = (wid & 7) * 16 + lr;        // col in [0,128)
    const int c1  = ((wid >> 3) << 7) + ec;     // GEMM1 col: r: ec, u: 128+ec
    const int kb0 = (wid >> 3) * 4;             // GEMM2 K-half base

    const float bias1 = rw ? sb1a[ec] : sb1b[ec];
    const float bias2 = rw ? sb2[ec] : 0.f;

    f32x4 hreg[5];
    #pragma unroll
    for (int mf = 0; mf < 5; ++mf) hreg[mf] = (f32x4){0.f, 0.f, 0.f, 0.f};

    for (int step = 0; step < T_STEPS; ++step) {
        // ---- phase0: f -> f segment (1280 tasks on 1024 threads) ---------
        for (int G = t; G < BN * 16; G += 1024) {
            const int node = G >> 4;
            const int pg   = G & 15;
            const int head = pg >> 3;
            const size_t bi = ((size_t)step * N_NODES + n0g + node) * 4;
            const float den = g_ndf[bi + head];
            const float num = g_ndf[bi + 2 + head];
            const float inv = 1.0f / (den + 1e-16f);
            short8 v;
            #pragma unroll
            for (int r = 0; r < 8; ++r) {
                const int c = pg * 8 + r;
                const float z = (num * swl[c] + den * sbl[c]) * inv + scb[c];
                v[r] = (short)f2bf(fsig(z));
            }
            const int gsw = pg ^ (node & 7);
            *(short8*)&featA[node * 384 + gsw * 8] = v;
        }
        __syncthreads();   // B1: f + hbf(prev epi2) visible

        // ---- GEMM1: M=80, K=256, this wave col c1 (hi+lo) ----------------
        f32x4 acc[5];
        #pragma unroll
        for (int mf = 0; mf < 5; ++mf)
            acc[mf] = (f32x4){bias1, bias1, bias1, bias1};
        #pragma unroll
        for (int half = 0; half < 2; ++half) {
            short8 wB[8];
            #pragma unroll
            for (int i = 0; i < 4; ++i) {
                const int kb = half * 4 + i;
                const int bidx = ((kb * 256 + c1) * 4 + lk) * 8;
                wB[2 * i]     = *(const short8*)&g_w1hi[bidx];
                wB[2 * i + 1] = *(const short8*)&g_w1lo[bidx];
            }
            #pragma unroll
            for (int i = 0; i < 4; ++i) {
                const int glin = (half * 4 + i) * 4 + lk;   // 0..31: f then hbf
                #pragma unroll
                for (int mf = 0; mf < 5; ++mf) {
                    const int row = mf * 16 + lr;
                    const short8 ah = *(short8*)&featA[row * 384 + (glin ^ (row & 7)) * 8];
                    acc[mf] = __builtin_amdgcn_mfma_f32_16x16x32_bf16(ah, wB[2 * i], acc[mf], 0, 0, 0);
                    acc[mf] = __builtin_amdgcn_mfma_f32_16x16x32_bf16(ah, wB[2 * i + 1], acc[mf], 0, 0, 0);
                }
            }
        }

        // ---- epi1: r-waves: rh -> rh segment; u-waves: u -> ubuf ---------
        if (rw) {
            #pragma unroll
            for (int mf = 0; mf < 5; ++mf) {
                #pragma unroll
                for (int j = 0; j < 4; ++j) {
                    const int row = mf * 16 + lk * 4 + j;
                    const float r  = fsig(acc[mf][j]);
                    const float rh = r * hreg[mf][j];
                    const float ot = __shfl_xor(rh, 1);
                    if ((lr & 1) == 0) {
                        const unsigned pk = (unsigned)f2bf(rh) | ((unsigned)f2bf(ot) << 16);
                        const int g  = (32 + (ec >> 3)) ^ (row & 7);
                        *(unsigned*)&featA[row * 384 + g * 8 + (ec & 7)] = pk;
                    }
                }
            }
        } else {
            #pragma unroll
            for (int mf = 0; mf < 5; ++mf) {
                #pragma unroll
                for (int j = 0; j < 4; ++j) {
                    const int row = mf * 16 + lk * 4 + j;
                    const float u  = fsig(acc[mf][j]);
                    const float ot = __shfl_xor(u, 1);
                    if ((lr & 1) == 0) {
                        const unsigned pk = (unsigned)f2bf(u) | ((unsigned)f2bf(ot) << 16);
                        *(unsigned*)&ubuf[row * 136 + ec] = pk;
                    }
                }
            }
        }
        __syncthreads();   // B2: rh + u visible

        // ---- GEMM2: N=128, K split: rw kb0-3 (f), uw kb4-7 (rh) ----------
        f32x4 acc2[5];
        #pragma unroll
        for (int mf = 0; mf < 5; ++mf)
            acc2[mf] = (f32x4){bias2, bias2, bias2, bias2};
        {
            short8 vB[8];
            #pragma unroll
            for (int i = 0; i < 4; ++i) {
                const int bidx = (((kb0 + i) * 128 + ec) * 4 + lk) * 8;
                vB[2 * i]     = *(const short8*)&g_w2hi[bidx];
                vB[2 * i + 1] = *(const short8*)&g_w2lo[bidx];
            }
            #pragma unroll
            for (int i = 0; i < 4; ++i) {
                const int glin = (kb0 + i) * 4 + lk;          // rw:0-15, uw:16-31
                const int gra  = (glin < 16) ? glin : glin + 16;  // rh at 32-47
                #pragma unroll
                for (int mf = 0; mf < 5; ++mf) {
                    const int row = mf * 16 + lr;
                    const short8 ah = *(short8*)&featA[row * 384 + (gra ^ (row & 7)) * 8];
                    acc2[mf] = __builtin_amdgcn_mfma_f32_16x16x32_bf16(ah, vB[2 * i], acc2[mf], 0, 0, 0);
                    acc2[mf] = __builtin_amdgcn_mfma_f32_16x16x32_bf16(ah, vB[2 * i + 1], acc2[mf], 0, 0, 0);
                }
            }
        }
        if (!rw) {
            #pragma unroll
            for (int mf = 0; mf < 5; ++mf) {
                #pragma unroll
                for (int j = 0; j < 4; ++j) {
                    const int row = mf * 16 + lk * 4 + j;
                    pbuf[row * 132 + ec] = acc2[mf][j];
                }
            }
        }
        __syncthreads();   // B3: partials visible; GEMM2 f-reads done

        // ---- epi2 (r-waves): c = tanh(low+high); h_new = c + u*(h-c) -----
        if (rw) {
            #pragma unroll
            for (int mf = 0; mf < 5; ++mf) {
                #pragma unroll
                for (int j = 0; j < 4; ++j) {
                    const int row = mf * 16 + lk * 4 + j;
                    const float zc = acc2[mf][j] + pbuf[row * 132 + ec];
                    const float c  = tanhf(zc);
                    const float u  = bf2f((unsigned short)ubuf[row * 136 + ec]);
                    const float hn = fmaf(u, hreg[mf][j] - c, c);
                    hreg[mf][j] = hn;
                    if (step < T_STEPS - 1) {
                        const float ot = __shfl_xor(hn, 1);
                        if ((lr & 1) == 0) {
                            const unsigned pk = (unsigned)f2bf(hn) | ((unsigned)f2bf(ot) << 16);
                            const int g  = (16 + (ec >> 3)) ^ (row & 7);
                            *(unsigned*)&featA[row * 384 + g * 8 + (ec & 7)] = pk;
                        }
                    } else {
                        hout[(size_t)(n0g + row) * HID + ec] = hn;
                    }
                }
            }
        }
        // next phase0 writes f segment only (disjoint from hbf/rh); B1 fences.
    }
}

// ---------------------------------------------------------------------------
extern "C" void kernel_launch(void* const* d_in, const int* in_sizes, int n_in,
                              void* d_out, int out_size, void* d_ws, size_t ws_size,
                              hipStream_t stream) {
    const float* x   = (const float*)d_in[0];
    const void*  ei  = d_in[1];
    // d_in[2] edge_weight: unused by the reference
    const float* W_l = (const float*)d_in[3];
    const float* b_l = (const float*)d_in[4];
    const float* W_r = (const float*)d_in[5];
    const float* b_r = (const float*)d_in[6];
    const float* att = (const float*)d_in[7];
    const float* cb  = (const float*)d_in[8];
    const float* W1  = (const float*)d_in[9];
    const float* b1  = (const float*)d_in[10];
    const float* W2  = (const float*)d_in[11];
    const float* b2  = (const float*)d_in[12];

    float* h = (float*)d_out;
    (void)d_ws; (void)ws_size;

    detect_kernel<<<1, 1, 0, stream>>>((const unsigned int*)ei);
    init_kernel<<<(T_STEPS * N_NODES + 255) / 256, 256, 0, stream>>>(x, ei);
    hist_kernel<<<(E_EDGES + 255) / 256, 256, 0, stream>>>(ei);
    scan_kernel<<<1, 1024, 0, stream>>>();
    scatter_kernel<<<(E_EDGES + 255) / 256, 256, 0, stream>>>(ei);
    prep_kernel<<<384, 256, 0, stream>>>(W1, W2, W_l, b_l, W_r, b_r, att);
    edge_all_kernel<<<dim3(157, T_STEPS), 256, 0, stream>>>(W_l, b_l, W_r, b_r, att);
    gru_all_kernel<<<N_NODES / BN, 1024, 0, stream>>>(W_l, b_l, cb, b1, b2, h);
}

// Round 8
// 382.524 us; speedup vs baseline: 1.1384x; 1.1384x over previous
//
#include <hip/hip_runtime.h>
#include <hip/hip_bf16.h>

#define N_NODES 20000
#define T_STEPS 8
#define E_EDGES 320000
#define HID 128
#define BN 80                          // nodes per gru block: 250 blocks exactly

typedef short short8 __attribute__((ext_vector_type(8)));
typedef float f32x4 __attribute__((ext_vector_type(4)));

// ---- all scratch in device globals: independent of ws_size ----------------
__device__ __attribute__((aligned(16))) float g_xT[T_STEPS * N_NODES];
__device__ __attribute__((aligned(16))) float g_ndf[T_STEPS * N_NODES * 4];
__device__ __attribute__((aligned(16))) int   g_cnt[N_NODES];
__device__ __attribute__((aligned(16))) int   g_rowptr[N_NODES + 1];
__device__ __attribute__((aligned(16))) int   g_cursor[N_NODES];
__device__ __attribute__((aligned(16))) int   g_sorted[E_EDGES];
__device__ __attribute__((aligned(16))) short g_w1hi[65536];
__device__ __attribute__((aligned(16))) short g_w1lo[65536];
__device__ __attribute__((aligned(16))) short g_w2hi[32768];
__device__ __attribute__((aligned(16))) short g_w2lo[32768];
__device__ float g_lin[6];            // P,Q,R per head
__device__ int   g_flag;

__device__ __forceinline__ float fsig(float z) {
    return 1.0f / (1.0f + __expf(-z));
}
__device__ __forceinline__ unsigned short f2bf(float f) {
    unsigned u = __builtin_bit_cast(unsigned, f);
    unsigned r = (u + 0x7FFFu + ((u >> 16) & 1u)) >> 16;   // RTNE
    return (unsigned short)r;
}
__device__ __forceinline__ float bf2f(unsigned short s) {
    return __builtin_bit_cast(float, ((unsigned)s) << 16);
}

// ---------------------------------------------------------------------------
__global__ void detect_kernel(const unsigned int* __restrict__ ei32) {
    int all_zero = 1;
    for (int k = 0; k < 64; ++k)
        if (ei32[2 * k + 1] != 0u) { all_zero = 0; break; }
    g_flag = all_zero;   // 1 => int64 layout
}

__device__ __forceinline__ void load_edge(const void* ei, int e, int& src, int& dst) {
    if (g_flag) {
        const long long* p = (const long long*)ei;
        src = (int)p[e]; dst = (int)p[E_EDGES + e];
    } else {
        const int* p = (const int*)ei;
        src = p[e]; dst = p[E_EDGES + e];
    }
}

// ---------------------------------------------------------------------------
__global__ __launch_bounds__(256) void init_kernel(
    const float* __restrict__ x, const void* __restrict__ ei)
{
    const int i = blockIdx.x * 256 + threadIdx.x;
    if (i < T_STEPS * N_NODES) {
        const int n = i >> 3, t = i & 7;
        g_xT[t * N_NODES + n] = x[i];
    }
    if (i < N_NODES) g_cnt[i] = 0;
}

__global__ __launch_bounds__(256) void hist_kernel(const void* __restrict__ ei) {
    const int e = blockIdx.x * 256 + threadIdx.x;
    if (e >= E_EDGES) return;
    int src, dst; load_edge(ei, e, src, dst);
    atomicAdd(&g_cnt[dst], 1);
}

// single block, 1024 threads: exclusive scan of g_cnt -> g_rowptr, g_cursor
__global__ __launch_bounds__(1024) void scan_kernel() {
    __shared__ int part[1024];
    const int tid  = threadIdx.x;
    const int base = tid * 20;
    int local[20];
    int s = 0;
    #pragma unroll
    for (int i = 0; i < 20; ++i) {
        const int n = base + i;
        const int c = (n < N_NODES) ? g_cnt[n] : 0;
        local[i] = s; s += c;
    }
    part[tid] = s;
    __syncthreads();
    for (int off = 1; off < 1024; off <<= 1) {
        const int v = (tid >= off) ? part[tid - off] : 0;
        __syncthreads();
        part[tid] += v;
        __syncthreads();
    }
    const int pre = (tid == 0) ? 0 : part[tid - 1];
    #pragma unroll
    for (int i = 0; i < 20; ++i) {
        const int n = base + i;
        if (n < N_NODES) {
            const int v = pre + local[i];
            g_rowptr[n] = v;
            g_cursor[n] = v;
        }
    }
    if (tid == 1023) g_rowptr[N_NODES] = part[1023];
}

__global__ __launch_bounds__(256) void scatter_kernel(const void* __restrict__ ei) {
    const int e = blockIdx.x * 256 + threadIdx.x;
    if (e >= E_EDGES) return;
    int src, dst; load_edge(ei, e, src, dst);
    const int pos = atomicAdd(&g_cursor[dst], 1);
    g_sorted[pos] = src;
}

// ---------------------------------------------------------------------------
// Prep: pack transposed bf16 hi/lo W1,W2 fragments; compute P,Q,R per head.
// Layout: idx = ((kb*NCOLS + n)*4 + kq)*8 + r  holds  W[kb*32+kq*8+r][n]
// ---------------------------------------------------------------------------
__global__ __launch_bounds__(256) void prep_kernel(
    const float* __restrict__ W1, const float* __restrict__ W2,
    const float* __restrict__ W_l, const float* __restrict__ b_l,
    const float* __restrict__ W_r, const float* __restrict__ b_r,
    const float* __restrict__ att)
{
    int i = blockIdx.x * 256 + threadIdx.x;   // 0 .. 98303
    if (i < 65536) {                          // W1: (256,256) [k][n]
        int k = i >> 8, n = i & 255;
        float w = W1[i];
        int kb = k >> 5, kq = (k >> 3) & 3, r = k & 7;
        int idx = ((kb * 256 + n) * 4 + kq) * 8 + r;
        unsigned short hi = f2bf(w);
        g_w1hi[idx] = (short)hi;
        g_w1lo[idx] = (short)f2bf(w - bf2f(hi));
    } else {                                  // W2: (256,128) [k][n]
        int j = i - 65536;
        int k = j >> 7, n = j & 127;
        float w = W2[j];
        int kb = k >> 5, kq = (k >> 3) & 3, r = k & 7;
        int idx = ((kb * 128 + n) * 4 + kq) * 8 + r;
        unsigned short hi = f2bf(w);
        g_w2hi[idx] = (short)hi;
        g_w2lo[idx] = (short)f2bf(w - bf2f(hi));
    }
    if (blockIdx.x == 0 && threadIdx.x < 2) {
        const int hh = threadIdx.x;
        float P = 0.f, Q = 0.f, R = 0.f;
        for (int k = 0; k < 64; ++k) {
            const int c = hh * 64 + k;
            const float a = att[c];
            P = fmaf(a, W_l[c], P);
            Q = fmaf(a, W_r[c], Q);
            R = fmaf(a, b_l[c] + b_r[c], R);
        }
        g_lin[hh * 3 + 0] = P;
        g_lin[hh * 3 + 1] = Q;
        g_lin[hh * 3 + 2] = R;
    }
}

// ---------------------------------------------------------------------------
// Edge pass, all 8 timesteps, no atomics, HEAD-FUSED: one thread per (node,t)
// computes both heads -> one gather per edge instead of two.
// ---------------------------------------------------------------------------
__global__ __launch_bounds__(256) void edge_all_kernel()
{
    __shared__ float4 ch4[128];   // (wl, wr, bs, at) for all 128 channels
    const int tid = threadIdx.x;
    // stage channel constants via g_lin? no: need raw per-channel -> passed via
    // globals g_w*? Channels come from original params; staged by caller args.
    // (filled below in kernel_launch wrapper kernel args)
    extern __shared__ float dummy[];   // unused
    (void)dummy;
    // ch4 is filled by the variant below; this body replaced.
}

// real edge kernel (takes param pointers)
__global__ __launch_bounds__(256) void edge_all2_kernel(
    const float* __restrict__ W_l, const float* __restrict__ b_l,
    const float* __restrict__ W_r, const float* __restrict__ b_r,
    const float* __restrict__ att)
{
    __shared__ float4 ch4[128];
    const int tid = threadIdx.x;
    if (tid < 128)
        ch4[tid] = make_float4(W_l[tid], W_r[tid], b_l[tid] + b_r[tid], att[tid]);
    __syncthreads();

    const int n = blockIdx.x * 256 + tid;
    const int t = blockIdx.y;
    if (n >= N_NODES) return;

    const float* xrow = &g_xT[t * N_NODES];
    const float xd = xrow[n];
    const float P0 = g_lin[0], Q0 = g_lin[1], R0 = g_lin[2];
    const float P1 = g_lin[3], Q1 = g_lin[4], R1 = g_lin[5];
    const float lin0 = fmaf(xd, Q0, R0);
    const float lin1 = fmaf(xd, Q1, R1);

    const int base = g_rowptr[n];
    const int deg  = g_rowptr[n + 1] - base;
    const int tot  = deg + 1;            // +1 = self loop at idx 0

    float den0 = 0.f, num0 = 0.f, den1 = 0.f, num1 = 0.f;
    for (int cs = 0; cs < tot; cs += 8) {
        int m = tot - cs; if (m > 8) m = 8;
        float xs[8];
        #pragma unroll
        for (int e = 0; e < 8; ++e) {
            xs[e] = 0.f;
            if (e < m) {
                const int idx = cs + e;
                xs[e] = (idx == 0) ? xd : xrow[g_sorted[base + idx - 1]];
            }
        }
        float ea0[8], ea1[8];
        #pragma unroll
        for (int e = 0; e < 8; ++e) { ea0[e] = 0.f; ea1[e] = 0.f; }
        #pragma unroll 2
        for (int c = 0; c < 64; ++c) {
            const float4 f0 = ch4[c];
            const float4 f1 = ch4[64 + c];
            const float dp0 = fmaf(xd, f0.y, f0.z);
            const float dp1 = fmaf(xd, f1.y, f1.z);
            #pragma unroll
            for (int e = 0; e < 8; ++e) {
                const float a0 = fmaf(xs[e], f0.x, dp0);
                ea0[e] = fmaf(fabsf(a0), f0.w, ea0[e]);
                const float a1 = fmaf(xs[e], f1.x, dp1);
                ea1[e] = fmaf(fabsf(a1), f1.w, ea1[e]);
            }
        }
        #pragma unroll
        for (int e = 0; e < 8; ++e) {
            if (e < m) {
                const float e0 = fmaf(0.6f, fmaf(xs[e], P0, lin0), 0.4f * ea0[e]);
                const float e1 = fmaf(0.6f, fmaf(xs[e], P1, lin1), 0.4f * ea1[e]);
                const float x0 = __expf(e0);
                const float x1 = __expf(e1);
                den0 += x0; num0 = fmaf(x0, xs[e], num0);
                den1 += x1; num1 = fmaf(x1, xs[e], num1);
            }
        }
    }
    float4 out = make_float4(den0, den1, num0, num1);
    *(float4*)&g_ndf[((size_t)t * N_NODES + n) * 4] = out;
}

// ---------------------------------------------------------------------------
// GRU v4: BN=80, 250 blocks, 512 threads (8 waves). h,u in REGISTERS via r/u
// column pairing (wave w: r-cols ec=[16w,16w+16), u-cols 128+ec, GEMM2 cols ec).
// featA row = 384 shorts: [f: g0-15 | hbf: g16-31 | rh: g32-47], XOR granule
// swizzle g^(node&7) (segment-preserving). 3 barriers/step. LDS ~63KB ->
// 2 blocks/CU. Plain __launch_bounds__(512): r4-proven 128-VGPR allocation.
// ---------------------------------------------------------------------------
__global__ __launch_bounds__(512) void gru_all_kernel(
    const float* __restrict__ W_l, const float* __restrict__ b_l,
    const float* __restrict__ conv_bias,
    const float* __restrict__ b1, const float* __restrict__ b2,
    float* __restrict__ hout)
{
    __shared__ short featA[BN * 384];   // 61440 B
    __shared__ float swl[128], sbl[128], scb[128];   // 1536 B

    const int t   = threadIdx.x;
    const int n0g = blockIdx.x * BN;

    if (t < 128) { swl[t] = W_l[t]; sbl[t] = b_l[t]; scb[t] = conv_bias[t]; }
    // zero hbf segment (granules 16..31): 1280 granule tasks
    for (int i = t; i < BN * 16; i += 512) {
        const int node = i >> 4;
        const int g    = 16 + (i & 15);
        const int gsw  = g ^ (node & 7);
        *(short8*)&featA[node * 384 + gsw * 8] = (short8)0;
    }
    __syncthreads();

    const int wid = t >> 6;
    const int l   = t & 63;
    const int lr  = l & 15;
    const int lk  = l >> 4;
    const int ec  = wid * 16 + lr;      // this wave's column set (r & GEMM2)

    const float bias_r = b1[ec];
    const float bias_u = b1[128 + ec];
    const float bias_2 = b2[ec];

    f32x4 hreg[5], ureg[5];
    #pragma unroll
    for (int mf = 0; mf < 5; ++mf) hreg[mf] = (f32x4){0.f, 0.f, 0.f, 0.f};

    for (int step = 0; step < T_STEPS; ++step) {
        // ---- phase0: f -> f segment (1280 tasks on 512 threads) ----------
        for (int G = t; G < BN * 16; G += 512) {
            const int node = G >> 4;
            const int pg   = G & 15;
            const int head = pg >> 3;
            const size_t bi = ((size_t)step * N_NODES + n0g + node) * 4;
            const float den = g_ndf[bi + head];
            const float num = g_ndf[bi + 2 + head];
            const float inv = 1.0f / (den + 1e-16f);
            short8 v;
            #pragma unroll
            for (int r = 0; r < 8; ++r) {
                const int c = pg * 8 + r;
                const float z = (num * swl[c] + den * sbl[c]) * inv + scb[c];
                v[r] = (short)f2bf(fsig(z));
            }
            const int gsw = pg ^ (node & 7);
            *(short8*)&featA[node * 384 + gsw * 8] = v;
        }
        __syncthreads();   // B1: f + hbf(prev epi2) visible

        // ---- GEMM1: M=80, K=256; cols ec (r, acc0) and 128+ec (u, acc1) --
        f32x4 acc0[5], acc1[5];
        #pragma unroll
        for (int mf = 0; mf < 5; ++mf) {
            acc0[mf] = (f32x4){bias_r, bias_r, bias_r, bias_r};
            acc1[mf] = (f32x4){bias_u, bias_u, bias_u, bias_u};
        }
        #pragma unroll
        for (int kb = 0; kb < 8; ++kb) {
            const int glin = kb * 4 + lk;                 // 0..31: f then hbf
            const int bidx0 = ((kb * 256 + ec) * 4 + lk) * 8;
            const int bidx1 = bidx0 + 4096;               // +128 cols
            const short8 bh0 = *(const short8*)&g_w1hi[bidx0];
            const short8 bl0 = *(const short8*)&g_w1lo[bidx0];
            const short8 bh1 = *(const short8*)&g_w1hi[bidx1];
            const short8 bl1 = *(const short8*)&g_w1lo[bidx1];
            #pragma unroll
            for (int mf = 0; mf < 5; ++mf) {
                const int row = mf * 16 + lr;
                const short8 ah = *(short8*)&featA[row * 384 + (glin ^ (row & 7)) * 8];
                acc0[mf] = __builtin_amdgcn_mfma_f32_16x16x32_bf16(ah, bh0, acc0[mf], 0, 0, 0);
                acc0[mf] = __builtin_amdgcn_mfma_f32_16x16x32_bf16(ah, bl0, acc0[mf], 0, 0, 0);
                acc1[mf] = __builtin_amdgcn_mfma_f32_16x16x32_bf16(ah, bh1, acc1[mf], 0, 0, 0);
                acc1[mf] = __builtin_amdgcn_mfma_f32_16x16x32_bf16(ah, bl1, acc1[mf], 0, 0, 0);
            }
        }

        // ---- epi1: r,u; ureg in regs; rh -> rh segment (packed dwords) ---
        #pragma unroll
        for (int mf = 0; mf < 5; ++mf) {
            #pragma unroll
            for (int j = 0; j < 4; ++j) {
                const int row = mf * 16 + lk * 4 + j;
                const float r = fsig(acc0[mf][j]);
                ureg[mf][j] = fsig(acc1[mf][j]);
                const float rh = r * hreg[mf][j];
                const float ot = __shfl_xor(rh, 1);
                if ((lr & 1) == 0) {
                    const unsigned pk = (unsigned)f2bf(rh) | ((unsigned)f2bf(ot) << 16);
                    const int g  = (32 + (ec >> 3)) ^ (row & 7);
                    *(unsigned*)&featA[row * 384 + g * 8 + (ec & 7)] = pk;
                }
            }
        }
        __syncthreads();   // B2: rh visible

        // ---- GEMM2: N=128, K=256; this wave col ec (full K) --------------
        f32x4 acc2[5];
        #pragma unroll
        for (int mf = 0; mf < 5; ++mf)
            acc2[mf] = (f32x4){bias_2, bias_2, bias_2, bias_2};
        #pragma unroll
        for (int kb = 0; kb < 8; ++kb) {
            const int glin = kb * 4 + lk;                       // 0..31
            const int gra  = (glin < 16) ? glin : glin + 16;    // rh at 32..47
            const int bidx = ((kb * 128 + ec) * 4 + lk) * 8;
            const short8 bh = *(const short8*)&g_w2hi[bidx];
            const short8 bl = *(const short8*)&g_w2lo[bidx];
            #pragma unroll
            for (int mf = 0; mf < 5; ++mf) {
                const int row = mf * 16 + lr;
                const short8 ah = *(short8*)&featA[row * 384 + (gra ^ (row & 7)) * 8];
                acc2[mf] = __builtin_amdgcn_mfma_f32_16x16x32_bf16(ah, bh, acc2[mf], 0, 0, 0);
                acc2[mf] = __builtin_amdgcn_mfma_f32_16x16x32_bf16(ah, bl, acc2[mf], 0, 0, 0);
            }
        }

        // ---- epi2: c = tanh; h_new = c + u*(h-c); hbf <- bf16(h_new) -----
        #pragma unroll
        for (int mf = 0; mf < 5; ++mf) {
            #pragma unroll
            for (int j = 0; j < 4; ++j) {
                const int row = mf * 16 + lk * 4 + j;
                const float c  = tanhf(acc2[mf][j]);
                const float hn = fmaf(ureg[mf][j], hreg[mf][j] - c, c);
                hreg[mf][j] = hn;
                if (step < T_STEPS - 1) {
                    const float ot = __shfl_xor(hn, 1);
                    if ((lr & 1) == 0) {
                        const unsigned pk = (unsigned)f2bf(hn) | ((unsigned)f2bf(ot) << 16);
                        const int g  = (16 + (ec >> 3)) ^ (row & 7);
                        *(unsigned*)&featA[row * 384 + g * 8 + (ec & 7)] = pk;
                    }
                } else {
                    hout[(size_t)(n0g + row) * HID + ec] = hn;
                }
            }
        }
        if (step < T_STEPS - 1)
            __syncthreads();   // B3: all GEMM2 f-reads done before next phase0
    }
}

// ---------------------------------------------------------------------------
extern "C" void kernel_launch(void* const* d_in, const int* in_sizes, int n_in,
                              void* d_out, int out_size, void* d_ws, size_t ws_size,
                              hipStream_t stream) {
    const float* x   = (const float*)d_in[0];
    const void*  ei  = d_in[1];
    // d_in[2] edge_weight: unused by the reference
    const float* W_l = (const float*)d_in[3];
    const float* b_l = (const float*)d_in[4];
    const float* W_r = (const float*)d_in[5];
    const float* b_r = (const float*)d_in[6];
    const float* att = (const float*)d_in[7];
    const float* cb  = (const float*)d_in[8];
    const float* W1  = (const float*)d_in[9];
    const float* b1  = (const float*)d_in[10];
    const float* W2  = (const float*)d_in[11];
    const float* b2  = (const float*)d_in[12];

    float* h = (float*)d_out;
    (void)d_ws; (void)ws_size;

    detect_kernel<<<1, 1, 0, stream>>>((const unsigned int*)ei);
    init_kernel<<<(T_STEPS * N_NODES + 255) / 256, 256, 0, stream>>>(x, ei);
    hist_kernel<<<(E_EDGES + 255) / 256, 256, 0, stream>>>(ei);
    scan_kernel<<<1, 1024, 0, stream>>>();
    scatter_kernel<<<(E_EDGES + 255) / 256, 256, 0, stream>>>(ei);
    prep_kernel<<<384, 256, 0, stream>>>(W1, W2, W_l, b_l, W_r, b_r, att);
    edge_all2_kernel<<<dim3((N_NODES + 255) / 256, T_STEPS), 256, 0, stream>>>(
        W_l, b_l, W_r, b_r, att);
    gru_all_kernel<<<N_NODES / BN, 512, 0, stream>>>(W_l, b_l, cb, b1, b2, h);
}

// Round 9
// 335.097 us; speedup vs baseline: 1.2995x; 1.1415x over previous
//
#include <hip/hip_runtime.h>
#include <hip/hip_bf16.h>

#define N_NODES 20000
#define T_STEPS 8
#define E_EDGES 320000
#define HID 128
#define BN 80                          // nodes per gru block: 250 blocks exactly

typedef short short8 __attribute__((ext_vector_type(8)));
typedef float f32x4 __attribute__((ext_vector_type(4)));

// ---- all scratch in device globals: independent of ws_size ----------------
__device__ __attribute__((aligned(16))) float g_xT[T_STEPS * N_NODES];
__device__ __attribute__((aligned(16))) float g_ndf[T_STEPS * N_NODES * 4];
__device__ __attribute__((aligned(16))) int   g_cnt[N_NODES];
__device__ __attribute__((aligned(16))) int   g_rowptr[N_NODES + 1];
__device__ __attribute__((aligned(16))) int   g_cursor[N_NODES];
__device__ __attribute__((aligned(16))) int   g_sorted[E_EDGES];
__device__ __attribute__((aligned(16))) short g_w1hi[65536];
__device__ __attribute__((aligned(16))) short g_w2hi[32768];
__device__ float g_lin[6];            // P,Q,R per head
__device__ int   g_flag;

__device__ __forceinline__ float frcp(float x) { return __builtin_amdgcn_rcpf(x); }
__device__ __forceinline__ float fsig(float z) { return frcp(1.f + __expf(-z)); }
__device__ __forceinline__ float ftanh(float z) {
    // 1 - 2/(e^{2z}+1); correct saturation at +/-inf via rcp(inf)=0
    return fmaf(-2.f, frcp(__expf(2.f * z) + 1.f), 1.f);
}
__device__ __forceinline__ unsigned cvtpk(float lo, float hi) {
    unsigned r;
    asm("v_cvt_pk_bf16_f32 %0, %1, %2" : "=v"(r) : "v"(lo), "v"(hi));
    return r;
}
__device__ __forceinline__ unsigned short f2bf(float f) {
    unsigned u = __builtin_bit_cast(unsigned, f);
    unsigned r = (u + 0x7FFFu + ((u >> 16) & 1u)) >> 16;   // RTNE
    return (unsigned short)r;
}

// ---------------------------------------------------------------------------
__device__ __forceinline__ void load_edge(const void* ei, int e, int& src, int& dst) {
    if (g_flag) {
        const long long* p = (const long long*)ei;
        src = (int)p[e]; dst = (int)p[E_EDGES + e];
    } else {
        const int* p = (const int*)ei;
        src = p[e]; dst = p[E_EDGES + e];
    }
}

// ---------------------------------------------------------------------------
// init: transpose x -> xT[t][n]; zero histogram; thread 0 detects int64/int32.
// ---------------------------------------------------------------------------
__global__ __launch_bounds__(256) void init_kernel(
    const float* __restrict__ x, const unsigned int* __restrict__ ei32)
{
    const int i = blockIdx.x * 256 + threadIdx.x;
    if (i < T_STEPS * N_NODES) {
        const int n = i >> 3, t = i & 7;
        g_xT[t * N_NODES + n] = x[i];
    }
    if (i < N_NODES) g_cnt[i] = 0;
    if (i == 0) {
        int all_zero = 1;
        for (int k = 0; k < 64; ++k)
            if (ei32[2 * k + 1] != 0u) { all_zero = 0; break; }
        g_flag = all_zero;   // 1 => int64 layout
    }
}

__global__ __launch_bounds__(256) void hist_kernel(const void* __restrict__ ei) {
    const int e = blockIdx.x * 256 + threadIdx.x;
    if (e >= E_EDGES) return;
    int src, dst; load_edge(ei, e, src, dst);
    atomicAdd(&g_cnt[dst], 1);
}

// single block, 1024 threads: exclusive scan of g_cnt -> g_rowptr, g_cursor
__global__ __launch_bounds__(1024) void scan_kernel() {
    __shared__ int part[1024];
    const int tid  = threadIdx.x;
    const int base = tid * 20;
    int local[20];
    int s = 0;
    #pragma unroll
    for (int i = 0; i < 20; ++i) {
        const int n = base + i;
        const int c = (n < N_NODES) ? g_cnt[n] : 0;
        local[i] = s; s += c;
    }
    part[tid] = s;
    __syncthreads();
    for (int off = 1; off < 1024; off <<= 1) {
        const int v = (tid >= off) ? part[tid - off] : 0;
        __syncthreads();
        part[tid] += v;
        __syncthreads();
    }
    const int pre = (tid == 0) ? 0 : part[tid - 1];
    #pragma unroll
    for (int i = 0; i < 20; ++i) {
        const int n = base + i;
        if (n < N_NODES) {
            const int v = pre + local[i];
            g_rowptr[n] = v;
            g_cursor[n] = v;
        }
    }
    if (tid == 1023) g_rowptr[N_NODES] = part[1023];
}

__global__ __launch_bounds__(256) void scatter_kernel(const void* __restrict__ ei) {
    const int e = blockIdx.x * 256 + threadIdx.x;
    if (e >= E_EDGES) return;
    int src, dst; load_edge(ei, e, src, dst);
    const int pos = atomicAdd(&g_cursor[dst], 1);
    g_sorted[pos] = src;
}

// ---------------------------------------------------------------------------
// Prep: pack transposed bf16 W1,W2 fragments; compute P,Q,R per head.
// Layout: idx = ((kb*NCOLS + n)*4 + kq)*8 + r  holds  W[kb*32+kq*8+r][n]
// ---------------------------------------------------------------------------
__global__ __launch_bounds__(256) void prep_kernel(
    const float* __restrict__ W1, const float* __restrict__ W2,
    const float* __restrict__ W_l, const float* __restrict__ b_l,
    const float* __restrict__ W_r, const float* __restrict__ b_r,
    const float* __restrict__ att)
{
    int i = blockIdx.x * 256 + threadIdx.x;   // 0 .. 98303
    if (i < 65536) {                          // W1: (256,256) [k][n]
        int k = i >> 8, n = i & 255;
        int kb = k >> 5, kq = (k >> 3) & 3, r = k & 7;
        g_w1hi[((kb * 256 + n) * 4 + kq) * 8 + r] = (short)f2bf(W1[i]);
    } else {                                  // W2: (256,128) [k][n]
        int j = i - 65536;
        int k = j >> 7, n = j & 127;
        int kb = k >> 5, kq = (k >> 3) & 3, r = k & 7;
        g_w2hi[((kb * 128 + n) * 4 + kq) * 8 + r] = (short)f2bf(W2[j]);
    }
    if (blockIdx.x == 0 && threadIdx.x < 2) {
        const int hh = threadIdx.x;
        float P = 0.f, Q = 0.f, R = 0.f;
        for (int k = 0; k < 64; ++k) {
            const int c = hh * 64 + k;
            const float a = att[c];
            P = fmaf(a, W_l[c], P);
            Q = fmaf(a, W_r[c], Q);
            R = fmaf(a, b_l[c] + b_r[c], R);
        }
        g_lin[hh * 3 + 0] = P;
        g_lin[hh * 3 + 1] = Q;
        g_lin[hh * 3 + 2] = R;
    }
}

// ---------------------------------------------------------------------------
// Edge pass: T-PAIRED (each thread handles t0=2*by and t0+1), head-fused,
// no atomics. One g_sorted index load serves 2 timesteps.
// ---------------------------------------------------------------------------
__global__ __launch_bounds__(256) void edge_all_kernel(
    const float* __restrict__ W_l, const float* __restrict__ b_l,
    const float* __restrict__ W_r, const float* __restrict__ b_r,
    const float* __restrict__ att)
{
    __shared__ float4 ch4[128];
    const int tid = threadIdx.x;
    if (tid < 128)
        ch4[tid] = make_float4(W_l[tid], W_r[tid], b_l[tid] + b_r[tid], att[tid]);
    __syncthreads();

    const int n  = blockIdx.x * 256 + tid;
    const int t0 = blockIdx.y * 2;
    if (n >= N_NODES) return;

    const float* xr0 = &g_xT[t0 * N_NODES];
    const float* xr1 = xr0 + N_NODES;
    const float xd0 = xr0[n];
    const float xd1 = xr1[n];
    const float P0 = g_lin[0], Q0 = g_lin[1], R0 = g_lin[2];
    const float P1 = g_lin[3], Q1 = g_lin[4], R1 = g_lin[5];
    const float l00 = fmaf(xd0, Q0, R0), l01 = fmaf(xd0, Q1, R1);
    const float l10 = fmaf(xd1, Q0, R0), l11 = fmaf(xd1, Q1, R1);

    const int base = g_rowptr[n];
    const int deg  = g_rowptr[n + 1] - base;
    const int tot  = deg + 1;            // +1 = self loop at idx 0

    float d00 = 0.f, n00 = 0.f, d01 = 0.f, n01 = 0.f;   // t0: head0, head1
    float d10 = 0.f, n10 = 0.f, d11 = 0.f, n11 = 0.f;   // t1
    for (int cs = 0; cs < tot; cs += 8) {
        int m = tot - cs; if (m > 8) m = 8;
        float xs0[8], xs1[8];
        #pragma unroll
        for (int e = 0; e < 8; ++e) {
            xs0[e] = 0.f; xs1[e] = 0.f;
            if (e < m) {
                const int idx = cs + e;
                if (idx == 0) { xs0[e] = xd0; xs1[e] = xd1; }
                else {
                    const int s = g_sorted[base + idx - 1];
                    xs0[e] = xr0[s]; xs1[e] = xr1[s];
                }
            }
        }
        float ea00[8], ea01[8], ea10[8], ea11[8];
        #pragma unroll
        for (int e = 0; e < 8; ++e) { ea00[e]=0.f; ea01[e]=0.f; ea10[e]=0.f; ea11[e]=0.f; }
        #pragma unroll 2
        for (int c = 0; c < 64; ++c) {
            const float4 f0 = ch4[c];
            const float4 f1 = ch4[64 + c];
            const float dp00 = fmaf(xd0, f0.y, f0.z);
            const float dp01 = fmaf(xd0, f1.y, f1.z);
            const float dp10 = fmaf(xd1, f0.y, f0.z);
            const float dp11 = fmaf(xd1, f1.y, f1.z);
            #pragma unroll
            for (int e = 0; e < 8; ++e) {
                float a;
                a = fmaf(xs0[e], f0.x, dp00); ea00[e] = fmaf(fabsf(a), f0.w, ea00[e]);
                a = fmaf(xs0[e], f1.x, dp01); ea01[e] = fmaf(fabsf(a), f1.w, ea01[e]);
                a = fmaf(xs1[e], f0.x, dp10); ea10[e] = fmaf(fabsf(a), f0.w, ea10[e]);
                a = fmaf(xs1[e], f1.x, dp11); ea11[e] = fmaf(fabsf(a), f1.w, ea11[e]);
            }
        }
        #pragma unroll
        for (int e = 0; e < 8; ++e) {
            if (e < m) {
                float ee, ex;
                ee = fmaf(0.6f, fmaf(xs0[e], P0, l00), 0.4f * ea00[e]);
                ex = __expf(ee); d00 += ex; n00 = fmaf(ex, xs0[e], n00);
                ee = fmaf(0.6f, fmaf(xs0[e], P1, l01), 0.4f * ea01[e]);
                ex = __expf(ee); d01 += ex; n01 = fmaf(ex, xs0[e], n01);
                ee = fmaf(0.6f, fmaf(xs1[e], P0, l10), 0.4f * ea10[e]);
                ex = __expf(ee); d10 += ex; n10 = fmaf(ex, xs1[e], n10);
                ee = fmaf(0.6f, fmaf(xs1[e], P1, l11), 0.4f * ea11[e]);
                ex = __expf(ee); d11 += ex; n11 = fmaf(ex, xs1[e], n11);
            }
        }
    }
    *(float4*)&g_ndf[((size_t)t0 * N_NODES + n) * 4]       = make_float4(d00, d01, n00, n01);
    *(float4*)&g_ndf[((size_t)(t0+1) * N_NODES + n) * 4]   = make_float4(d10, d11, n10, n11);
}

// ---------------------------------------------------------------------------
// GRU v5: BN=80, 250 blocks, 512 threads (8 waves). Single-bf16 weights.
// h,u in registers via r/u column pairing. featA row = 384 shorts:
// [f: g0-15 | hbf: g16-31 | rh: g32-47], XOR swizzle g^(row&7).
// GEMM2's f-half fused into the GEMM1 phase (shares A-fragments) ->
// only 2 barriers/step: B1 (f+hbf ready), B2 (rh ready).
// ---------------------------------------------------------------------------
__global__ __launch_bounds__(512) void gru_all_kernel(
    const float* __restrict__ W_l, const float* __restrict__ b_l,
    const float* __restrict__ conv_bias,
    const float* __restrict__ b1, const float* __restrict__ b2,
    float* __restrict__ hout)
{
    __shared__ short featA[BN * 384];   // 61440 B
    __shared__ float swl[128], sbl[128], scb[128];   // 1536 B

    const int t   = threadIdx.x;
    const int n0g = blockIdx.x * BN;

    if (t < 128) { swl[t] = W_l[t]; sbl[t] = b_l[t]; scb[t] = conv_bias[t]; }
    // zero hbf segment (granules 16..31)
    for (int i = t; i < BN * 16; i += 512) {
        const int node = i >> 4;
        const int g    = 16 + (i & 15);
        const int gsw  = g ^ (node & 7);
        *(short8*)&featA[node * 384 + gsw * 8] = (short8)0;
    }
    __syncthreads();

    const int wid = t >> 6;
    const int l   = t & 63;
    const int lr  = l & 15;
    const int lk  = l >> 4;
    const int ec  = wid * 16 + lr;      // this wave's column set (r & GEMM2)

    const float bias_r = b1[ec];
    const float bias_u = b1[128 + ec];
    const float bias_2 = b2[ec];

    f32x4 hreg[5], ureg[5];
    #pragma unroll
    for (int mf = 0; mf < 5; ++mf) hreg[mf] = (f32x4){0.f, 0.f, 0.f, 0.f};

    for (int step = 0; step < T_STEPS; ++step) {
        // ---- phase0: f -> f segment (1280 tasks on 512 threads) ----------
        for (int G = t; G < BN * 16; G += 512) {
            const int node = G >> 4;
            const int pg   = G & 15;
            const int head = pg >> 3;
            const size_t bi = ((size_t)step * N_NODES + n0g + node) * 4;
            const float den = g_ndf[bi + head];
            const float num = g_ndf[bi + 2 + head];
            const float inv = frcp(den + 1e-16f);
            union { unsigned u[4]; short8 s; } P;
            #pragma unroll
            for (int r2 = 0; r2 < 4; ++r2) {
                const int c0 = pg * 8 + 2 * r2;
                const float z0 = (num * swl[c0]     + den * sbl[c0])     * inv + scb[c0];
                const float z1 = (num * swl[c0 + 1] + den * sbl[c0 + 1]) * inv + scb[c0 + 1];
                P.u[r2] = cvtpk(fsig(z0), fsig(z1));
            }
            const int gsw = pg ^ (node & 7);
            *(short8*)&featA[node * 384 + gsw * 8] = P.s;
        }
        __syncthreads();   // B1: f + hbf(prev epi2) visible

        // ---- GEMM1 (cols ec, 128+ec) + GEMM2 f-half (col ec), K=256 ------
        f32x4 acc0[5], acc1[5], acc2[5];
        #pragma unroll
        for (int mf = 0; mf < 5; ++mf) {
            acc0[mf] = (f32x4){bias_r, bias_r, bias_r, bias_r};
            acc1[mf] = (f32x4){bias_u, bias_u, bias_u, bias_u};
            acc2[mf] = (f32x4){bias_2, bias_2, bias_2, bias_2};
        }
        #pragma unroll
        for (int kb = 0; kb < 8; ++kb) {
            const int glin = kb * 4 + lk;                 // 0..31: f then hbf
            const int bidx0 = ((kb * 256 + ec) * 4 + lk) * 8;
            const short8 b1a = *(const short8*)&g_w1hi[bidx0];
            const short8 b1b = *(const short8*)&g_w1hi[bidx0 + 4096];
            short8 b2f;
            if (kb < 4) b2f = *(const short8*)&g_w2hi[((kb * 128 + ec) * 4 + lk) * 8];
            #pragma unroll
            for (int mf = 0; mf < 5; ++mf) {
                const int row = mf * 16 + lr;
                const short8 ah = *(short8*)&featA[row * 384 + (glin ^ (row & 7)) * 8];
                acc0[mf] = __builtin_amdgcn_mfma_f32_16x16x32_bf16(ah, b1a, acc0[mf], 0, 0, 0);
                acc1[mf] = __builtin_amdgcn_mfma_f32_16x16x32_bf16(ah, b1b, acc1[mf], 0, 0, 0);
                if (kb < 4)
                    acc2[mf] = __builtin_amdgcn_mfma_f32_16x16x32_bf16(ah, b2f, acc2[mf], 0, 0, 0);
            }
        }

        // ---- epi1: r,u; ureg in regs; rh -> rh segment (cvt_pk dwords) ---
        #pragma unroll
        for (int mf = 0; mf < 5; ++mf) {
            #pragma unroll
            for (int j = 0; j < 4; ++j) {
                const int row = mf * 16 + lk * 4 + j;
                const float r = fsig(acc0[mf][j]);
                ureg[mf][j] = fsig(acc1[mf][j]);
                const float rh = r * hreg[mf][j];
                const float ot = __shfl_xor(rh, 1);
                if ((lr & 1) == 0) {
                    const int g = (32 + (ec >> 3)) ^ (row & 7);
                    *(unsigned*)&featA[row * 384 + g * 8 + (ec & 7)] = cvtpk(rh, ot);
                }
            }
        }
        __syncthreads();   // B2: rh visible

        // ---- GEMM2 rh-half: kb 4..7, granules 32..47 ---------------------
        #pragma unroll
        for (int kb = 4; kb < 8; ++kb) {
            const int gra = kb * 4 + lk + 16;             // 32..47
            const short8 b2f = *(const short8*)&g_w2hi[((kb * 128 + ec) * 4 + lk) * 8];
            #pragma unroll
            for (int mf = 0; mf < 5; ++mf) {
                const int row = mf * 16 + lr;
                const short8 ah = *(short8*)&featA[row * 384 + (gra ^ (row & 7)) * 8];
                acc2[mf] = __builtin_amdgcn_mfma_f32_16x16x32_bf16(ah, b2f, acc2[mf], 0, 0, 0);
            }
        }

        // ---- epi2: c = tanh; h_new = c + u*(h-c); hbf <- bf16(h_new) -----
        #pragma unroll
        for (int mf = 0; mf < 5; ++mf) {
            #pragma unroll
            for (int j = 0; j < 4; ++j) {
                const int row = mf * 16 + lk * 4 + j;
                const float c  = ftanh(acc2[mf][j]);
                const float hn = fmaf(ureg[mf][j], hreg[mf][j] - c, c);
                hreg[mf][j] = hn;
                if (step < T_STEPS - 1) {
                    const float ot = __shfl_xor(hn, 1);
                    if ((lr & 1) == 0) {
                        const int g = (16 + (ec >> 3)) ^ (row & 7);
                        *(unsigned*)&featA[row * 384 + g * 8 + (ec & 7)] = cvtpk(hn, ot);
                    }
                } else {
                    hout[(size_t)(n0g + row) * HID + ec] = hn;
                }
            }
        }
        // no trailing barrier: next phase0 writes f only (disjoint segments);
        // B1 fences epi2's hbf writes before GEMM1 reads; B2 fences the f-reads
        // of [GEMM1+GEMM2f] before the following phase0 overwrite.
    }
}

// ---------------------------------------------------------------------------
extern "C" void kernel_launch(void* const* d_in, const int* in_sizes, int n_in,
                              void* d_out, int out_size, void* d_ws, size_t ws_size,
                              hipStream_t stream) {
    const float* x   = (const float*)d_in[0];
    const void*  ei  = d_in[1];
    // d_in[2] edge_weight: unused by the reference
    const float* W_l = (const float*)d_in[3];
    const float* b_l = (const float*)d_in[4];
    const float* W_r = (const float*)d_in[5];
    const float* b_r = (const float*)d_in[6];
    const float* att = (const float*)d_in[7];
    const float* cb  = (const float*)d_in[8];
    const float* W1  = (const float*)d_in[9];
    const float* b1  = (const float*)d_in[10];
    const float* W2  = (const float*)d_in[11];
    const float* b2  = (const float*)d_in[12];

    float* h = (float*)d_out;
    (void)d_ws; (void)ws_size;

    init_kernel<<<(T_STEPS * N_NODES + 255) / 256, 256, 0, stream>>>(
        x, (const unsigned int*)ei);
    hist_kernel<<<(E_EDGES + 255) / 256, 256, 0, stream>>>(ei);
    scan_kernel<<<1, 1024, 0, stream>>>();
    scatter_kernel<<<(E_EDGES + 255) / 256, 256, 0, stream>>>(ei);
    prep_kernel<<<384, 256, 0, stream>>>(W1, W2, W_l, b_l, W_r, b_r, att);
    edge_all_kernel<<<dim3((N_NODES + 255) / 256, T_STEPS / 2), 256, 0, stream>>>(
        W_l, b_l, W_r, b_r, att);
    gru_all_kernel<<<N_NODES / BN, 512, 0, stream>>>(W_l, b_l, cb, b1, b2, h);
}